// Round 1
// baseline (563.111 us; speedup 1.0000x reference)
//
#include <hip/hip_runtime.h>
#include <cstdint>
#include <cstddef>

// Problem constants
#define NB 4
#define C 128
#define P 4096      // HR*WR
#define S 64
#define Q 4096      // HS*WS
#define WS_DIM 64
#define HS_DIM 64

// workspace layout (float offsets)
#define FR_T_OFF 0          // (N,P,C)  8MB
#define FS_T_OFF 2097152    // (N,Q,C)  8MB
#define G_T_OFF  4194304    // (N,P,S,2) 8MB
#define M_T_OFF  6291456    // (N,P,S)  4MB
// total 7,340,032 floats = 28MB

// Generic per-batch transpose (R x 4096) -> (4096 x R), R in {128, 64}.
// blocks: [0,2048) feat_ref | [2048,4096) feat_src | [4096,6144) grids | [6144,7168) mask
__global__ __launch_bounds__(256) void transpose_many(
    const float* __restrict__ fr, const float* __restrict__ fs,
    const float* __restrict__ gr, const float* __restrict__ mk,
    float* __restrict__ ws) {
  __shared__ float tile[32][33];
  int b = blockIdx.x;
  const float* src; float* dst; int R; int tb;
  if (b < 2048)      { src = fr; dst = ws + FR_T_OFF; R = 128; tb = b; }
  else if (b < 4096) { src = fs; dst = ws + FS_T_OFF; R = 128; tb = b - 2048; }
  else if (b < 6144) { src = gr; dst = ws + G_T_OFF;  R = 128; tb = b - 4096; }
  else               { src = mk; dst = ws + M_T_OFF;  R = 64;  tb = b - 6144; }
  int rt = R >> 5;              // row tiles per batch: 4 or 2
  int per_n = rt * (P >> 5);    // 512 or 256
  int n   = tb / per_n;
  int t   = tb - n * per_n;
  int rti = t & (rt - 1);
  int cti = t / rt;
  int r0 = rti << 5, c0 = cti << 5;
  const float* Sp = src + (size_t)n * R * P;
  float*       Dp = dst + (size_t)n * R * P;
  int tx = threadIdx.x, ty = threadIdx.y;
#pragma unroll
  for (int i = 0; i < 4; ++i)
    tile[ty + 8 * i][tx] = Sp[(size_t)(r0 + ty + 8 * i) * P + (c0 + tx)];
  __syncthreads();
#pragma unroll
  for (int i = 0; i < 4; ++i)
    Dp[(size_t)(c0 + ty + 8 * i) * R + (r0 + tx)] = tile[tx][ty + 8 * i];
}

// One wave per (n, p). 4 waves per block -> 4 consecutive p.
// Phase 1: lane = s, compute bilinear weights/indices + mask, stash in LDS.
// Phase 2: lane = (s_local<<2)|chan_group; 4 rounds of 16 samples; each lane
//          does 32 channels x 4 neighbors of fp32 dot; 2-shuffle reduce.
__global__ __launch_bounds__(256) void corr_main(
    const float* __restrict__ ws, float* __restrict__ out, float* __restrict__ cmo) {
  const float* fr_t = ws + FR_T_OFF;
  const float* fs_t = ws + FS_T_OFF;
  const float* g_t  = ws + G_T_OFF;
  const float* m_t  = ws + M_T_OFF;

  __shared__ int4   s_idx[4][64];
  __shared__ float4 s_w[4][64];
  __shared__ float  s_cmm[4][64];
  __shared__ float  s_out[4][64];

  int b    = blockIdx.x;
  // XCD-aware swizzle: xcd = b&7 (round-robin dispatch heuristic);
  // each XCD works on exactly one batch n -> its 2MB feat_src fits the 4MB L2.
  int xcd  = b & 7;
  int n    = xcd >> 1;
  int half = xcd & 1;
  int grp  = b >> 3;                  // [0,512)
  int wv   = threadIdx.x >> 6;
  int lane = threadIdx.x & 63;
  int p_base = ((half << 9) + grp) << 2;   // 4*(half*512+grp) in [0,4096)
  int p      = p_base + wv;

  // ---------------- phase 1: lane = s ----------------
  {
    const float2 g2 = *reinterpret_cast<const float2*>(
        &g_t[((size_t)(n * P + p) * S + lane) * 2]);
    float mval = m_t[(size_t)(n * P + p) * S + lane];
    float ix = g2.x - 0.5f, iy = g2.y - 0.5f;
    float x0f = floorf(ix), y0f = floorf(iy);
    float wx1 = ix - x0f, wy1 = iy - y0f;
    float wx0 = 1.0f - wx1, wy0 = 1.0f - wy1;
    int x0 = (int)x0f, y0 = (int)y0f;
    int4 idx; float4 w4;
    float msum = 0.0f;
    // reference order: (dx,dy) = (0,0),(0,1),(1,0),(1,1)
    {
      int xi = x0, yi = y0;
      bool inb = (xi >= 0) & (xi < WS_DIM) & (yi >= 0) & (yi < HS_DIM);
      float wk = inb ? wx0 * wy0 : 0.0f;
      msum += wk;
      idx.x = min(max(yi, 0), HS_DIM - 1) * WS_DIM + min(max(xi, 0), WS_DIM - 1);
      w4.x = wk;
    }
    {
      int xi = x0, yi = y0 + 1;
      bool inb = (xi >= 0) & (xi < WS_DIM) & (yi >= 0) & (yi < HS_DIM);
      float wk = inb ? wx0 * wy1 : 0.0f;
      msum += wk;
      idx.y = min(max(yi, 0), HS_DIM - 1) * WS_DIM + min(max(xi, 0), WS_DIM - 1);
      w4.y = wk;
    }
    {
      int xi = x0 + 1, yi = y0;
      bool inb = (xi >= 0) & (xi < WS_DIM) & (yi >= 0) & (yi < HS_DIM);
      float wk = inb ? wx1 * wy0 : 0.0f;
      msum += wk;
      idx.z = min(max(yi, 0), HS_DIM - 1) * WS_DIM + min(max(xi, 0), WS_DIM - 1);
      w4.z = wk;
    }
    {
      int xi = x0 + 1, yi = y0 + 1;
      bool inb = (xi >= 0) & (xi < WS_DIM) & (yi >= 0) & (yi < HS_DIM);
      float wk = inb ? wx1 * wy1 : 0.0f;
      msum += wk;
      idx.w = min(max(yi, 0), HS_DIM - 1) * WS_DIM + min(max(xi, 0), WS_DIM - 1);
      w4.w = wk;
    }
    float cm  = (msum < 0.9999f) ? 0.0f : 1.0f;
    float cmm = cm * mval;
    s_idx[wv][lane] = idx;
    s_w[wv][lane]   = w4;
    s_cmm[wv][lane] = cmm;
  }
  __syncthreads();

  // cooperative corr_mask store (16B-chunked across the block)
  {
    int t = threadIdx.x;
    int s = t >> 2, w2 = t & 3;
    cmo[(size_t)(n * S + s) * P + (p_base + w2)] = s_cmm[w2][s];
  }

  // ---------------- phase 2 ----------------
  int cg = lane & 3;    // channel group: 32 channels each
  int sl = lane >> 2;   // sample slot within round: 16 samples/round
  float4 fr[8];
  {
    const float4* frp = reinterpret_cast<const float4*>(
        &fr_t[(size_t)(n * P + p) * C + cg * 32]);
#pragma unroll
    for (int j = 0; j < 8; ++j) fr[j] = frp[j];
  }
  const float* fsb = fs_t + (size_t)n * Q * C + cg * 32;

#pragma unroll 1
  for (int r = 0; r < 4; ++r) {
    int s = r * 16 + sl;
    int4   id4 = s_idx[wv][s];
    float4 w4  = s_w[wv][s];
    float  cms = s_cmm[wv][s];
    int   kid[4] = {id4.x, id4.y, id4.z, id4.w};
    float kw[4]  = {w4.x, w4.y, w4.z, w4.w};
    float acc = 0.0f;
#pragma unroll
    for (int k = 0; k < 4; ++k) {
      const float4* q = reinterpret_cast<const float4*>(fsb + (size_t)kid[k] * C);
      float d = 0.0f;
#pragma unroll
      for (int j = 0; j < 8; ++j) {
        float4 a = q[j];
        d = fmaf(fr[j].x, a.x, d);
        d = fmaf(fr[j].y, a.y, d);
        d = fmaf(fr[j].z, a.z, d);
        d = fmaf(fr[j].w, a.w, d);
      }
      acc = fmaf(kw[k], d, acc);
    }
    // reduce across the 4 channel-groups (lanes sl*4 .. sl*4+3)
    acc += __shfl_xor(acc, 1);
    acc += __shfl_xor(acc, 2);
    if (cg == 0) s_out[wv][s] = acc * cms;
  }
  __syncthreads();
  {
    int t = threadIdx.x;
    int s = t >> 2, w2 = t & 3;
    out[(size_t)(n * S + s) * P + (p_base + w2)] = s_out[w2][s];
  }
}

extern "C" void kernel_launch(void* const* d_in, const int* in_sizes, int n_in,
                              void* d_out, int out_size, void* d_ws, size_t ws_size,
                              hipStream_t stream) {
  const float* feat_ref = (const float*)d_in[0];  // (4,128,64,64)
  const float* feat_src = (const float*)d_in[1];  // (4,128,64,64)
  const float* grids    = (const float*)d_in[2];  // (4,64,2,64,64)
  const float* mask     = (const float*)d_in[3];  // (4,64,64,64)
  float* ws  = (float*)d_ws;                      // needs 28MB
  float* out = (float*)d_out;                     // out: 1,048,576 floats
  float* cmo = out + (size_t)NB * S * P;          // then corr_mask: 1,048,576

  transpose_many<<<7168, dim3(32, 8), 0, stream>>>(feat_ref, feat_src, grids, mask, ws);
  corr_main<<<4096, 256, 0, stream>>>(ws, out, cmo);
}

// Round 3
// 218.802 us; speedup vs baseline: 2.5736x; 2.5736x over previous
//
#include <hip/hip_runtime.h>
#include <cstdint>
#include <cstddef>

// Problem constants
#define NB 4
#define C 128
#define P 4096      // HR*WR
#define S 64
#define Q 4096      // HS*WS
#define WS_DIM 64
#define HS_DIM 64

// workspace layout (float offsets) — only the two feature transposes now
#define FR_T_OFF 0          // (N,P,C)  8MB
#define FS_T_OFF 2097152    // (N,Q,C)  8MB

// float4-vectorized per-batch transpose (128 x 4096) -> (4096 x 128)
// for feat_ref and feat_src only. 1024 blocks each.
__global__ __launch_bounds__(256) void transpose_feat(
    const float* __restrict__ fr, const float* __restrict__ fs,
    float* __restrict__ ws) {
  __shared__ float tile[32][65];
  int b = blockIdx.x;
  const float* src = (b < 1024) ? fr : fs;
  float* dst = ws + ((b < 1024) ? FR_T_OFF : FS_T_OFF);
  int tb = b & 1023;
  int n  = tb >> 8;          // 256 tiles per batch
  int t  = tb & 255;
  int rti = t & 3;           // 4 row-tiles of 32 channels
  int cti = t >> 2;          // 64 col-tiles of 64 pixels
  int r0 = rti << 5, c0 = cti << 6;
  const float* Sp = src + (size_t)n * C * P;
  float*       Dp = dst + (size_t)n * C * P;
  int tx = threadIdx.x & 15, ty = threadIdx.x >> 4;   // 16 x 16
#pragma unroll
  for (int i = 0; i < 2; ++i) {
    int row = ty + 16 * i;
    float4 v = *reinterpret_cast<const float4*>(
        &Sp[(size_t)(r0 + row) * P + c0 + tx * 4]);
    tile[row][tx * 4 + 0] = v.x;
    tile[row][tx * 4 + 1] = v.y;
    tile[row][tx * 4 + 2] = v.z;
    tile[row][tx * 4 + 3] = v.w;
  }
  __syncthreads();
  int ox = threadIdx.x & 7, oy = threadIdx.x >> 3;    // 8 x 32
#pragma unroll
  for (int i = 0; i < 2; ++i) {
    int prow = oy + 32 * i;
    float4 v = make_float4(tile[ox * 4 + 0][prow], tile[ox * 4 + 1][prow],
                           tile[ox * 4 + 2][prow], tile[ox * 4 + 3][prow]);
    *reinterpret_cast<float4*>(&Dp[(size_t)(c0 + prow) * C + r0 + ox * 4]) = v;
  }
}

// One wave per (n, p). 4 waves per block -> 4 consecutive p.
// Phase 1: lane = s, compute bilinear weights/indices + mask (grids/mask read
//          directly from global, strided), stash in LDS.
// Phase 2: lane = (sl<<2)|cg. INTERLEAVED channel mapping: lane cg owns
//          channels {j*16 + cg*4 .. +3}, so at fixed (j,k) the 4 lanes of a
//          sample read one fully-consumed 64B line (16 lines/instr, was 64).
__global__ __launch_bounds__(256) void corr_main(
    const float* __restrict__ ws,
    const float* __restrict__ grids, const float* __restrict__ mask,
    float* __restrict__ out, float* __restrict__ cmo) {
  const float* fr_t = ws + FR_T_OFF;
  const float* fs_t = ws + FS_T_OFF;

  __shared__ int4   s_idx[4][64];
  __shared__ float4 s_w[4][64];
  __shared__ float  s_cmm[4][64];
  __shared__ float  s_out[4][64];

  int b    = blockIdx.x;
  // XCD-aware swizzle: xcd = b&7; each XCD sees one batch n -> 2MB fs_t fits
  // the 4MB per-XCD L2.
  int xcd  = b & 7;
  int n    = xcd >> 1;
  int half = xcd & 1;
  int grp  = b >> 3;                  // [0,512)
  int wv   = threadIdx.x >> 6;
  int lane = threadIdx.x & 63;
  int p_base = ((half << 9) + grp) << 2;   // 4*(half*512+grp) in [0,4096)
  int p      = p_base + wv;

  // ---------------- phase 1: lane = s ----------------
  {
    float gx = grids[(((size_t)n * S + lane) * 2 + 0) * P + p];
    float gy = grids[(((size_t)n * S + lane) * 2 + 1) * P + p];
    float mval = mask[((size_t)n * S + lane) * P + p];
    float ix = gx - 0.5f, iy = gy - 0.5f;
    float x0f = floorf(ix), y0f = floorf(iy);
    float wx1 = ix - x0f, wy1 = iy - y0f;
    float wx0 = 1.0f - wx1, wy0 = 1.0f - wy1;
    int x0 = (int)x0f, y0 = (int)y0f;
    int4 idx; float4 w4;
    float msum = 0.0f;
    {
      int xi = x0, yi = y0;
      bool inb = (xi >= 0) & (xi < WS_DIM) & (yi >= 0) & (yi < HS_DIM);
      float wk = inb ? wx0 * wy0 : 0.0f;
      msum += wk;
      idx.x = min(max(yi, 0), HS_DIM - 1) * WS_DIM + min(max(xi, 0), WS_DIM - 1);
      w4.x = wk;
    }
    {
      int xi = x0, yi = y0 + 1;
      bool inb = (xi >= 0) & (xi < WS_DIM) & (yi >= 0) & (yi < HS_DIM);
      float wk = inb ? wx0 * wy1 : 0.0f;
      msum += wk;
      idx.y = min(max(yi, 0), HS_DIM - 1) * WS_DIM + min(max(xi, 0), WS_DIM - 1);
      w4.y = wk;
    }
    {
      int xi = x0 + 1, yi = y0;
      bool inb = (xi >= 0) & (xi < WS_DIM) & (yi >= 0) & (yi < HS_DIM);
      float wk = inb ? wx1 * wy0 : 0.0f;
      msum += wk;
      idx.z = min(max(yi, 0), HS_DIM - 1) * WS_DIM + min(max(xi, 0), WS_DIM - 1);
      w4.z = wk;
    }
    {
      int xi = x0 + 1, yi = y0 + 1;
      bool inb = (xi >= 0) & (xi < WS_DIM) & (yi >= 0) & (yi < HS_DIM);
      float wk = inb ? wx1 * wy1 : 0.0f;
      msum += wk;
      idx.w = min(max(yi, 0), HS_DIM - 1) * WS_DIM + min(max(xi, 0), WS_DIM - 1);
      w4.w = wk;
    }
    float cm  = (msum < 0.9999f) ? 0.0f : 1.0f;
    float cmm = cm * mval;
    s_idx[wv][lane] = idx;
    s_w[wv][lane]   = w4;
    s_cmm[wv][lane] = cmm;
  }
  __syncthreads();

  // cooperative corr_mask store (16B chunks: 4 consecutive p per 4 threads)
  {
    int t = threadIdx.x;
    int s = t >> 2, w2 = t & 3;
    cmo[(size_t)(n * S + s) * P + (p_base + w2)] = s_cmm[w2][s];
  }

  // ---------------- phase 2 ----------------
  int cg = lane & 3;    // 4 lanes per sample, interleaved channel slices
  int sl = lane >> 2;   // 16 samples per round
  float4 fr[8];
  {
    const float* frp = &fr_t[(size_t)(n * P + p) * C + cg * 4];
#pragma unroll
    for (int j = 0; j < 8; ++j)
      fr[j] = *reinterpret_cast<const float4*>(frp + j * 16);
  }
  const float* fsb = fs_t + (size_t)n * Q * C + cg * 4;

#pragma unroll 1
  for (int r = 0; r < 4; ++r) {
    int s = r * 16 + sl;
    int4   id4 = s_idx[wv][s];
    float4 w4  = s_w[wv][s];
    float  cms = s_cmm[wv][s];
    int   kid[4] = {id4.x, id4.y, id4.z, id4.w};
    float kw[4]  = {w4.x, w4.y, w4.z, w4.w};
    float acc = 0.0f;
#pragma unroll
    for (int k = 0; k < 4; ++k) {
      const float* qb = fsb + (size_t)kid[k] * C;
      float d = 0.0f;
#pragma unroll
      for (int j = 0; j < 8; ++j) {
        float4 a = *reinterpret_cast<const float4*>(qb + j * 16);
        d = fmaf(fr[j].x, a.x, d);
        d = fmaf(fr[j].y, a.y, d);
        d = fmaf(fr[j].z, a.z, d);
        d = fmaf(fr[j].w, a.w, d);
      }
      acc = fmaf(kw[k], d, acc);
    }
    // reduce across the 4 channel-group lanes
    acc += __shfl_xor(acc, 1);
    acc += __shfl_xor(acc, 2);
    if (cg == 0) s_out[wv][s] = acc * cms;
  }
  __syncthreads();
  {
    int t = threadIdx.x;
    int s = t >> 2, w2 = t & 3;
    out[(size_t)(n * S + s) * P + (p_base + w2)] = s_out[w2][s];
  }
}

extern "C" void kernel_launch(void* const* d_in, const int* in_sizes, int n_in,
                              void* d_out, int out_size, void* d_ws, size_t ws_size,
                              hipStream_t stream) {
  const float* feat_ref = (const float*)d_in[0];  // (4,128,64,64)
  const float* feat_src = (const float*)d_in[1];  // (4,128,64,64)
  const float* grids    = (const float*)d_in[2];  // (4,64,2,64,64)
  const float* mask     = (const float*)d_in[3];  // (4,64,64,64)
  float* ws  = (float*)d_ws;                      // needs 16MB
  float* out = (float*)d_out;                     // out: 1,048,576 floats
  float* cmo = out + (size_t)NB * S * P;          // then corr_mask

  transpose_feat<<<2048, 256, 0, stream>>>(feat_ref, feat_src, ws);
  corr_main<<<4096, 256, 0, stream>>>(ws, grids, mask, out, cmo);
}

// Round 4
// 206.710 us; speedup vs baseline: 2.7242x; 1.0585x over previous
//
#include <hip/hip_runtime.h>
#include <cstdint>
#include <cstddef>

// Problem constants
#define NB 4
#define C 128
#define P 4096      // HR*WR
#define S 64
#define Q 4096      // HS*WS
#define WS_DIM 64
#define HS_DIM 64

// workspace: fs transpose only, (N,Q,C) float = 8MB
#define FS_T_OFF 0

// float4-vectorized per-batch transpose (128 x 4096) -> (4096 x 128), fs only.
__global__ __launch_bounds__(256) void transpose_fs(
    const float* __restrict__ fs, float* __restrict__ ws) {
  __shared__ float tile[32][65];
  int b = blockIdx.x;          // [0,1024)
  int n  = b >> 8;             // 256 tiles per batch
  int t  = b & 255;
  int rti = t & 3;             // 4 row-tiles of 32 channels
  int cti = t >> 2;            // 64 col-tiles of 64 pixels
  int r0 = rti << 5, c0 = cti << 6;
  const float* Sp = fs + (size_t)n * C * P;
  float*       Dp = ws + FS_T_OFF + (size_t)n * C * P;
  int tx = threadIdx.x & 15, ty = threadIdx.x >> 4;   // 16 x 16
#pragma unroll
  for (int i = 0; i < 2; ++i) {
    int row = ty + 16 * i;
    float4 v = *reinterpret_cast<const float4*>(
        &Sp[(size_t)(r0 + row) * P + c0 + tx * 4]);
    tile[row][tx * 4 + 0] = v.x;
    tile[row][tx * 4 + 1] = v.y;
    tile[row][tx * 4 + 2] = v.z;
    tile[row][tx * 4 + 3] = v.w;
  }
  __syncthreads();
  int ox = threadIdx.x & 7, oy = threadIdx.x >> 3;    // 8 x 32
#pragma unroll
  for (int i = 0; i < 2; ++i) {
    int prow = oy + 32 * i;
    float4 v = make_float4(tile[ox * 4 + 0][prow], tile[ox * 4 + 1][prow],
                           tile[ox * 4 + 2][prow], tile[ox * 4 + 3][prow]);
    *reinterpret_cast<float4*>(&Dp[(size_t)(c0 + prow) * C + r0 + ox * 4]) = v;
  }
}

// One wave per (n, p); 4 waves/block = 4 consecutive p.
// Phase 0: cooperative fr stage (C,P layout -> LDS [4][128]).
// Phase 1: thread t handles (s=t>>2, po=t&3): bilinear weights/idx/mask,
//          coalesced-ish grids/mask reads; cmo stored from registers.
// Phase 2: lane=(sl<<2)|cg, interleaved channels; gathers batched 2 neighbor
//          rows (16 float4) at a time into registers for deep MLP... er, MLP
//          no: for deep memory-level parallelism, then FMA.
__global__ __launch_bounds__(256) void corr_main(
    const float* __restrict__ ws, const float* __restrict__ fr_g,
    const float* __restrict__ grids, const float* __restrict__ mask,
    float* __restrict__ out, float* __restrict__ cmo) {
  const float* fs_t = ws + FS_T_OFF;

  __shared__ int4   s_idx[4][64];
  __shared__ float4 s_w[4][64];
  __shared__ float  s_cmm[4][64];
  __shared__ float  s_out[4][64];
  __shared__ float  fr_lds[4][128];

  int b    = blockIdx.x;
  // XCD-aware swizzle: xcd = b&7; each XCD sees one batch n -> 2MB fs_t fits
  // the 4MB per-XCD L2.
  int xcd  = b & 7;
  int n    = xcd >> 1;
  int half = xcd & 1;
  int grp  = b >> 3;                  // [0,512)
  int wv   = threadIdx.x >> 6;
  int lane = threadIdx.x & 63;
  int t    = threadIdx.x;
  int p_base = ((half << 9) + grp) << 2;   // 4*(half*512+grp) in [0,4096)
  int p      = p_base + wv;

  // ---------------- phase 0: stage fr for the block's 4 pixels ----------------
#pragma unroll
  for (int i = 0; i < 2; ++i) {
    int e  = t + 256 * i;          // [0,512)
    int c  = e >> 2;
    int po = e & 3;
    fr_lds[po][c] = fr_g[((size_t)n * C + c) * P + p_base + po];
  }

  // ---------------- phase 1: thread t -> (s, po) ----------------
  {
    int s  = t >> 2;
    int po = t & 3;
    int pp = p_base + po;
    float gx = grids[(((size_t)n * S + s) * 2 + 0) * P + pp];
    float gy = grids[(((size_t)n * S + s) * 2 + 1) * P + pp];
    float mval = mask[((size_t)n * S + s) * P + pp];
    float ix = gx - 0.5f, iy = gy - 0.5f;
    float x0f = floorf(ix), y0f = floorf(iy);
    float wx1 = ix - x0f, wy1 = iy - y0f;
    float wx0 = 1.0f - wx1, wy0 = 1.0f - wy1;
    int x0 = (int)x0f, y0 = (int)y0f;
    int4 idx; float4 w4;
    float msum = 0.0f;
    {
      int xi = x0, yi = y0;
      bool inb = (xi >= 0) & (xi < WS_DIM) & (yi >= 0) & (yi < HS_DIM);
      float wk = inb ? wx0 * wy0 : 0.0f;
      msum += wk;
      idx.x = min(max(yi, 0), HS_DIM - 1) * WS_DIM + min(max(xi, 0), WS_DIM - 1);
      w4.x = wk;
    }
    {
      int xi = x0, yi = y0 + 1;
      bool inb = (xi >= 0) & (xi < WS_DIM) & (yi >= 0) & (yi < HS_DIM);
      float wk = inb ? wx0 * wy1 : 0.0f;
      msum += wk;
      idx.y = min(max(yi, 0), HS_DIM - 1) * WS_DIM + min(max(xi, 0), WS_DIM - 1);
      w4.y = wk;
    }
    {
      int xi = x0 + 1, yi = y0;
      bool inb = (xi >= 0) & (xi < WS_DIM) & (yi >= 0) & (yi < HS_DIM);
      float wk = inb ? wx1 * wy0 : 0.0f;
      msum += wk;
      idx.z = min(max(yi, 0), HS_DIM - 1) * WS_DIM + min(max(xi, 0), WS_DIM - 1);
      w4.z = wk;
    }
    {
      int xi = x0 + 1, yi = y0 + 1;
      bool inb = (xi >= 0) & (xi < WS_DIM) & (yi >= 0) & (yi < HS_DIM);
      float wk = inb ? wx1 * wy1 : 0.0f;
      msum += wk;
      idx.w = min(max(yi, 0), HS_DIM - 1) * WS_DIM + min(max(xi, 0), WS_DIM - 1);
      w4.w = wk;
    }
    float cm  = (msum < 0.9999f) ? 0.0f : 1.0f;
    float cmm = cm * mval;
    s_idx[po][s] = idx;
    s_w[po][s]   = w4;
    s_cmm[po][s] = cmm;
    cmo[((size_t)n * S + s) * P + pp] = cmm;   // store directly
  }
  __syncthreads();

  // ---------------- phase 2 ----------------
  int cg = lane & 3;    // 4 lanes per sample, interleaved channel slices
  int sl = lane >> 2;   // 16 samples per round
  float4 fr[8];
#pragma unroll
  for (int j = 0; j < 8; ++j)
    fr[j] = *reinterpret_cast<const float4*>(&fr_lds[wv][j * 16 + cg * 4]);
  const float* fsb = fs_t + (size_t)n * Q * C + cg * 4;

#pragma unroll 1
  for (int r = 0; r < 4; ++r) {
    int s = r * 16 + sl;
    int4   id4 = s_idx[wv][s];
    float4 w4  = s_w[wv][s];
    float  cms = s_cmm[wv][s];
    const float* q0 = fsb + id4.x * C;
    const float* q1 = fsb + id4.y * C;
    const float* q2 = fsb + id4.z * C;
    const float* q3 = fsb + id4.w * C;

    // neighbors 0,1: issue all 16 loads, then FMA
    float4 a0[8], a1[8];
#pragma unroll
    for (int j = 0; j < 8; ++j) a0[j] = *reinterpret_cast<const float4*>(q0 + j * 16);
#pragma unroll
    for (int j = 0; j < 8; ++j) a1[j] = *reinterpret_cast<const float4*>(q1 + j * 16);
    float d0 = 0.0f, d1 = 0.0f;
#pragma unroll
    for (int j = 0; j < 8; ++j) {
      d0 = fmaf(fr[j].x, a0[j].x, d0);
      d0 = fmaf(fr[j].y, a0[j].y, d0);
      d0 = fmaf(fr[j].z, a0[j].z, d0);
      d0 = fmaf(fr[j].w, a0[j].w, d0);
      d1 = fmaf(fr[j].x, a1[j].x, d1);
      d1 = fmaf(fr[j].y, a1[j].y, d1);
      d1 = fmaf(fr[j].z, a1[j].z, d1);
      d1 = fmaf(fr[j].w, a1[j].w, d1);
    }
    // neighbors 2,3
    float4 b0[8], b1[8];
#pragma unroll
    for (int j = 0; j < 8; ++j) b0[j] = *reinterpret_cast<const float4*>(q2 + j * 16);
#pragma unroll
    for (int j = 0; j < 8; ++j) b1[j] = *reinterpret_cast<const float4*>(q3 + j * 16);
    float d2 = 0.0f, d3 = 0.0f;
#pragma unroll
    for (int j = 0; j < 8; ++j) {
      d2 = fmaf(fr[j].x, b0[j].x, d2);
      d2 = fmaf(fr[j].y, b0[j].y, d2);
      d2 = fmaf(fr[j].z, b0[j].z, d2);
      d2 = fmaf(fr[j].w, b0[j].w, d2);
      d3 = fmaf(fr[j].x, b1[j].x, d3);
      d3 = fmaf(fr[j].y, b1[j].y, d3);
      d3 = fmaf(fr[j].z, b1[j].z, d3);
      d3 = fmaf(fr[j].w, b1[j].w, d3);
    }
    float acc = fmaf(w4.x, d0, 0.0f);
    acc = fmaf(w4.y, d1, acc);
    acc = fmaf(w4.z, d2, acc);
    acc = fmaf(w4.w, d3, acc);
    // reduce across the 4 channel-group lanes
    acc += __shfl_xor(acc, 1);
    acc += __shfl_xor(acc, 2);
    if (cg == 0) s_out[wv][s] = acc * cms;
  }
  __syncthreads();
  {
    int s = t >> 2, w2 = t & 3;
    out[((size_t)n * S + s) * P + (p_base + w2)] = s_out[w2][s];
  }
}

extern "C" void kernel_launch(void* const* d_in, const int* in_sizes, int n_in,
                              void* d_out, int out_size, void* d_ws, size_t ws_size,
                              hipStream_t stream) {
  const float* feat_ref = (const float*)d_in[0];  // (4,128,64,64)
  const float* feat_src = (const float*)d_in[1];  // (4,128,64,64)
  const float* grids    = (const float*)d_in[2];  // (4,64,2,64,64)
  const float* mask     = (const float*)d_in[3];  // (4,64,64,64)
  float* ws  = (float*)d_ws;                      // needs 8MB
  float* out = (float*)d_out;                     // out: 1,048,576 floats
  float* cmo = out + (size_t)NB * S * P;          // then corr_mask

  transpose_fs<<<1024, 256, 0, stream>>>(feat_src, ws);
  corr_main<<<4096, 256, 0, stream>>>(ws, feat_ref, grids, mask, out, cmo);
}

// Round 5
// 144.146 us; speedup vs baseline: 3.9065x; 1.4340x over previous
//
#include <hip/hip_runtime.h>
#include <hip/hip_fp16.h>
#include <cstdint>
#include <cstddef>

// Problem constants
#define NB 4
#define C 128
#define P 4096      // HR*WR
#define S 64
#define Q 4096      // HS*WS
#define WS_DIM 64
#define HS_DIM 64

// workspace: fs transposed + fp16-converted, (N,Q,C) half = 4MB
#define FS_T_OFF 0

// per-batch transpose (128 x 4096) fp32 -> (4096 x 128) fp16.
__global__ __launch_bounds__(256) void transpose_fs_h(
    const float* __restrict__ fs, __half* __restrict__ ws) {
  __shared__ float tile[32][65];
  int b = blockIdx.x;          // [0,1024)
  int n  = b >> 8;             // 256 tiles per batch
  int t  = b & 255;
  int rti = t & 3;             // 4 row-tiles of 32 channels
  int cti = t >> 2;            // 64 col-tiles of 64 pixels
  int r0 = rti << 5, c0 = cti << 6;
  const float* Sp = fs + (size_t)n * C * P;
  __half*      Dp = ws + FS_T_OFF + (size_t)n * Q * C;
  int tx = threadIdx.x & 15, ty = threadIdx.x >> 4;   // 16 x 16
#pragma unroll
  for (int i = 0; i < 2; ++i) {
    int row = ty + 16 * i;
    float4 v = *reinterpret_cast<const float4*>(
        &Sp[(size_t)(r0 + row) * P + c0 + tx * 4]);
    tile[row][tx * 4 + 0] = v.x;
    tile[row][tx * 4 + 1] = v.y;
    tile[row][tx * 4 + 2] = v.z;
    tile[row][tx * 4 + 3] = v.w;
  }
  __syncthreads();
  int ox = threadIdx.x & 7, oy = threadIdx.x >> 3;    // 8 x 32
#pragma unroll
  for (int i = 0; i < 2; ++i) {
    int prow = oy + 32 * i;
    __half2 h01 = __floats2half2_rn(tile[ox * 4 + 0][prow], tile[ox * 4 + 1][prow]);
    __half2 h23 = __floats2half2_rn(tile[ox * 4 + 2][prow], tile[ox * 4 + 3][prow]);
    uint2 pk;
    pk.x = *reinterpret_cast<unsigned int*>(&h01);
    pk.y = *reinterpret_cast<unsigned int*>(&h23);
    *reinterpret_cast<uint2*>(&Dp[(size_t)(c0 + prow) * C + r0 + ox * 4]) = pk;
  }
}

// One wave per (n, p); 4 waves/block = 4 consecutive p.
// Phase 0: cooperative fr stage (fp32, (C,P) layout -> LDS [4][132]).
// Phase 1: thread t -> (s=t>>2, po=t&3): bilinear weights/idx/mask in fp32
//          (exactly as reference); cmo stored from registers.
// Phase 2: lane=(sl<<2)|cg; lane cg owns channels {j*32+cg*8..+8} (j=0..3):
//          4 lanes x 16B(8 halfs) = one fully-consumed 64B line per sample
//          per (neighbor,j). fp16 fs halves the gathered-line count (the
//          ~2.5cy/line TA wall is the binding constraint).
__global__ __launch_bounds__(256) void corr_main(
    const __half* __restrict__ ws, const float* __restrict__ fr_g,
    const float* __restrict__ grids, const float* __restrict__ mask,
    float* __restrict__ out, float* __restrict__ cmo) {
  const __half* fs_h = ws + FS_T_OFF;

  __shared__ int4   s_idx[4][65];
  __shared__ float4 s_w[4][65];
  __shared__ float  s_cmm[4][68];
  __shared__ float  s_out[4][68];
  __shared__ float  fr_lds[4][132];

  int b    = blockIdx.x;
  // XCD-aware swizzle: xcd = b&7; each XCD sees one batch n -> 2MB fs_h fits
  // the 4MB per-XCD L2 easily.
  int xcd  = b & 7;
  int n    = xcd >> 1;
  int half = xcd & 1;
  int grp  = b >> 3;                  // [0,512)
  int wv   = threadIdx.x >> 6;
  int lane = threadIdx.x & 63;
  int t    = threadIdx.x;
  int p_base = ((half << 9) + grp) << 2;   // 4*(half*512+grp) in [0,4096)
  int p      = p_base + wv;
  (void)p;

  // ---------------- phase 0: stage fr (fp32) for the block's 4 pixels --------
#pragma unroll
  for (int i = 0; i < 2; ++i) {
    int e  = t + 256 * i;          // [0,512)
    int c  = e >> 2;
    int po = e & 3;
    fr_lds[po][c] = fr_g[((size_t)n * C + c) * P + p_base + po];
  }

  // ---------------- phase 1: thread t -> (s, po) ----------------
  {
    int s  = t >> 2;
    int po = t & 3;
    int pp = p_base + po;
    float gx = grids[(((size_t)n * S + s) * 2 + 0) * P + pp];
    float gy = grids[(((size_t)n * S + s) * 2 + 1) * P + pp];
    float mval = mask[((size_t)n * S + s) * P + pp];
    float ix = gx - 0.5f, iy = gy - 0.5f;
    float x0f = floorf(ix), y0f = floorf(iy);
    float wx1 = ix - x0f, wy1 = iy - y0f;
    float wx0 = 1.0f - wx1, wy0 = 1.0f - wy1;
    int x0 = (int)x0f, y0 = (int)y0f;
    int4 idx; float4 w4;
    float msum = 0.0f;
    {
      int xi = x0, yi = y0;
      bool inb = (xi >= 0) & (xi < WS_DIM) & (yi >= 0) & (yi < HS_DIM);
      float wk = inb ? wx0 * wy0 : 0.0f;
      msum += wk;
      idx.x = min(max(yi, 0), HS_DIM - 1) * WS_DIM + min(max(xi, 0), WS_DIM - 1);
      w4.x = wk;
    }
    {
      int xi = x0, yi = y0 + 1;
      bool inb = (xi >= 0) & (xi < WS_DIM) & (yi >= 0) & (yi < HS_DIM);
      float wk = inb ? wx0 * wy1 : 0.0f;
      msum += wk;
      idx.y = min(max(yi, 0), HS_DIM - 1) * WS_DIM + min(max(xi, 0), WS_DIM - 1);
      w4.y = wk;
    }
    {
      int xi = x0 + 1, yi = y0;
      bool inb = (xi >= 0) & (xi < WS_DIM) & (yi >= 0) & (yi < HS_DIM);
      float wk = inb ? wx1 * wy0 : 0.0f;
      msum += wk;
      idx.z = min(max(yi, 0), HS_DIM - 1) * WS_DIM + min(max(xi, 0), WS_DIM - 1);
      w4.z = wk;
    }
    {
      int xi = x0 + 1, yi = y0 + 1;
      bool inb = (xi >= 0) & (xi < WS_DIM) & (yi >= 0) & (yi < HS_DIM);
      float wk = inb ? wx1 * wy1 : 0.0f;
      msum += wk;
      idx.w = min(max(yi, 0), HS_DIM - 1) * WS_DIM + min(max(xi, 0), WS_DIM - 1);
      w4.w = wk;
    }
    float cm  = (msum < 0.9999f) ? 0.0f : 1.0f;
    float cmm = cm * mval;
    s_idx[po][s] = idx;
    s_w[po][s]   = w4;
    s_cmm[po][s] = cmm;
    cmo[((size_t)n * S + s) * P + pp] = cmm;   // store directly
  }
  __syncthreads();

  // ---------------- phase 2 ----------------
  int cg = lane & 3;    // 4 lanes per sample; lane cg owns ch {j*32+cg*8..+8}
  int sl = lane >> 2;   // 16 samples per round
  float frv[4][8];
#pragma unroll
  for (int j = 0; j < 4; ++j) {
    float4 a = *reinterpret_cast<const float4*>(&fr_lds[wv][j * 32 + cg * 8]);
    float4 bq = *reinterpret_cast<const float4*>(&fr_lds[wv][j * 32 + cg * 8 + 4]);
    frv[j][0] = a.x; frv[j][1] = a.y; frv[j][2] = a.z; frv[j][3] = a.w;
    frv[j][4] = bq.x; frv[j][5] = bq.y; frv[j][6] = bq.z; frv[j][7] = bq.w;
  }
  const __half* fsb = fs_h + (size_t)n * Q * C + cg * 8;

#pragma unroll 1
  for (int r = 0; r < 4; ++r) {
    int s = r * 16 + sl;
    int4   id4 = s_idx[wv][s];
    float4 w4  = s_w[wv][s];
    float  cms = s_cmm[wv][s];
    const __half* q0 = fsb + (size_t)id4.x * C;
    const __half* q1 = fsb + (size_t)id4.y * C;
    const __half* q2 = fsb + (size_t)id4.z * C;
    const __half* q3 = fsb + (size_t)id4.w * C;
    float d0 = 0.0f, d1 = 0.0f, d2 = 0.0f, d3 = 0.0f;
#pragma unroll
    for (int j = 0; j < 4; ++j) {
      uint4 v0 = *reinterpret_cast<const uint4*>(q0 + j * 32);
      uint4 v1 = *reinterpret_cast<const uint4*>(q1 + j * 32);
      uint4 v2 = *reinterpret_cast<const uint4*>(q2 + j * 32);
      uint4 v3 = *reinterpret_cast<const uint4*>(q3 + j * 32);
      const __half2* h0 = reinterpret_cast<const __half2*>(&v0);
      const __half2* h1 = reinterpret_cast<const __half2*>(&v1);
      const __half2* h2 = reinterpret_cast<const __half2*>(&v2);
      const __half2* h3 = reinterpret_cast<const __half2*>(&v3);
#pragma unroll
      for (int i = 0; i < 4; ++i) {
        float2 f0 = __half22float2(h0[i]);
        float2 f1 = __half22float2(h1[i]);
        float2 f2 = __half22float2(h2[i]);
        float2 f3 = __half22float2(h3[i]);
        d0 = fmaf(frv[j][2 * i], f0.x, d0);
        d0 = fmaf(frv[j][2 * i + 1], f0.y, d0);
        d1 = fmaf(frv[j][2 * i], f1.x, d1);
        d1 = fmaf(frv[j][2 * i + 1], f1.y, d1);
        d2 = fmaf(frv[j][2 * i], f2.x, d2);
        d2 = fmaf(frv[j][2 * i + 1], f2.y, d2);
        d3 = fmaf(frv[j][2 * i], f3.x, d3);
        d3 = fmaf(frv[j][2 * i + 1], f3.y, d3);
      }
    }
    float acc = fmaf(w4.x, d0, 0.0f);
    acc = fmaf(w4.y, d1, acc);
    acc = fmaf(w4.z, d2, acc);
    acc = fmaf(w4.w, d3, acc);
    // reduce across the 4 channel-group lanes
    acc += __shfl_xor(acc, 1);
    acc += __shfl_xor(acc, 2);
    if (cg == 0) s_out[wv][s] = acc * cms;
  }
  __syncthreads();
  {
    int s = t >> 2, w2 = t & 3;
    out[((size_t)n * S + s) * P + (p_base + w2)] = s_out[w2][s];
  }
}

extern "C" void kernel_launch(void* const* d_in, const int* in_sizes, int n_in,
                              void* d_out, int out_size, void* d_ws, size_t ws_size,
                              hipStream_t stream) {
  const float* feat_ref = (const float*)d_in[0];  // (4,128,64,64)
  const float* feat_src = (const float*)d_in[1];  // (4,128,64,64)
  const float* grids    = (const float*)d_in[2];  // (4,64,2,64,64)
  const float* mask     = (const float*)d_in[3];  // (4,64,64,64)
  __half* ws = (__half*)d_ws;                     // needs 4MB
  float* out = (float*)d_out;                     // out: 1,048,576 floats
  float* cmo = out + (size_t)NB * S * P;          // then corr_mask

  transpose_fs_h<<<1024, 256, 0, stream>>>(feat_src, ws);
  corr_main<<<4096, 256, 0, stream>>>(ws, feat_ref, grids, mask, out, cmo);
}

// Round 6
// 132.719 us; speedup vs baseline: 4.2429x; 1.0861x over previous
//
#include <hip/hip_runtime.h>
#include <hip/hip_fp16.h>
#include <cstdint>
#include <cstddef>

// Problem constants
#define NB 4
#define C 128
#define P 4096      // HR*WR
#define S 64
#define Q 4096      // HS*WS
#define WS_DIM 64
#define HS_DIM 64

// workspace: fs transposed + fp16-converted, (N,Q,C) half = 4MB
#define FS_T_OFF 0

// direct-to-LDS 16B gather (per-lane global addr, wave-linear LDS dest)
__device__ __forceinline__ void gload_lds16(const void* g, void* l) {
  __builtin_amdgcn_global_load_lds(
      (const __attribute__((address_space(1))) unsigned int*)g,
      (__attribute__((address_space(3))) unsigned int*)l, 16, 0, 0);
}

// per-batch transpose (128 x 4096) fp32 -> (4096 x 128) fp16.
__global__ __launch_bounds__(256) void transpose_fs_h(
    const float* __restrict__ fs, __half* __restrict__ ws) {
  __shared__ float tile[32][65];
  int b = blockIdx.x;          // [0,1024)
  int n  = b >> 8;             // 256 tiles per batch
  int t  = b & 255;
  int rti = t & 3;             // 4 row-tiles of 32 channels
  int cti = t >> 2;            // 64 col-tiles of 64 pixels
  int r0 = rti << 5, c0 = cti << 6;
  const float* Sp = fs + (size_t)n * C * P;
  __half*      Dp = ws + FS_T_OFF + (size_t)n * Q * C;
  int tx = threadIdx.x & 15, ty = threadIdx.x >> 4;   // 16 x 16
#pragma unroll
  for (int i = 0; i < 2; ++i) {
    int row = ty + 16 * i;
    float4 v = *reinterpret_cast<const float4*>(
        &Sp[(size_t)(r0 + row) * P + c0 + tx * 4]);
    tile[row][tx * 4 + 0] = v.x;
    tile[row][tx * 4 + 1] = v.y;
    tile[row][tx * 4 + 2] = v.z;
    tile[row][tx * 4 + 3] = v.w;
  }
  __syncthreads();
  int ox = threadIdx.x & 7, oy = threadIdx.x >> 3;    // 8 x 32
#pragma unroll
  for (int i = 0; i < 2; ++i) {
    int prow = oy + 32 * i;
    __half2 h01 = __floats2half2_rn(tile[ox * 4 + 0][prow], tile[ox * 4 + 1][prow]);
    __half2 h23 = __floats2half2_rn(tile[ox * 4 + 2][prow], tile[ox * 4 + 3][prow]);
    uint2 pk;
    pk.x = *reinterpret_cast<unsigned int*>(&h01);
    pk.y = *reinterpret_cast<unsigned int*>(&h23);
    *reinterpret_cast<uint2*>(&Dp[(size_t)(c0 + prow) * C + r0 + ox * 4]) = pk;
  }
}

// One wave per (n, p); 4 waves/block = 4 consecutive p.
// Phase 0: cooperative fr stage (fp32 -> LDS [4][132]).
// Phase 1: thread t -> (s=t>>2, po=t&3): bilinear weights/idx/mask fp32.
// Phase 2: per r-iter each wave ISSUES all 16 gathers via global_load_lds
//          into its private 16KB staging buffer (256 lines in flight),
//          then vmcnt(8)->compute k0,k1, vmcnt(0)->compute k2,k3.
//          Tests latency-vs-throughput for the ~2.5cy/line gather wall.
__global__ __launch_bounds__(256) void corr_main(
    const __half* __restrict__ ws, const float* __restrict__ fr_g,
    const float* __restrict__ grids, const float* __restrict__ mask,
    float* __restrict__ out, float* __restrict__ cmo) {
  const __half* fs_h = ws + FS_T_OFF;

  __shared__ __align__(16) unsigned char stg[4][16384];
  __shared__ int4   s_idx[4][65];
  __shared__ float4 s_w[4][65];
  __shared__ float  s_cmm[4][68];
  __shared__ float  s_out[4][68];
  __shared__ float  fr_lds[4][132];

  int b    = blockIdx.x;
  // XCD-aware swizzle: xcd = b&7; each XCD sees one batch n -> 2MB fs_h fits
  // the 4MB per-XCD L2 easily.
  int xcd  = b & 7;
  int n    = xcd >> 1;
  int half = xcd & 1;
  int grp  = b >> 3;                  // [0,512)
  int wv   = threadIdx.x >> 6;
  int lane = threadIdx.x & 63;
  int t    = threadIdx.x;
  int p_base = ((half << 9) + grp) << 2;   // 4*(half*512+grp) in [0,4096)

  // ---------------- phase 0: stage fr (fp32) for the block's 4 pixels --------
#pragma unroll
  for (int i = 0; i < 2; ++i) {
    int e  = t + 256 * i;          // [0,512)
    int c  = e >> 2;
    int po = e & 3;
    fr_lds[po][c] = fr_g[((size_t)n * C + c) * P + p_base + po];
  }

  // ---------------- phase 1: thread t -> (s, po) ----------------
  {
    int s  = t >> 2;
    int po = t & 3;
    int pp = p_base + po;
    float gx = grids[(((size_t)n * S + s) * 2 + 0) * P + pp];
    float gy = grids[(((size_t)n * S + s) * 2 + 1) * P + pp];
    float mval = mask[((size_t)n * S + s) * P + pp];
    float ix = gx - 0.5f, iy = gy - 0.5f;
    float x0f = floorf(ix), y0f = floorf(iy);
    float wx1 = ix - x0f, wy1 = iy - y0f;
    float wx0 = 1.0f - wx1, wy0 = 1.0f - wy1;
    int x0 = (int)x0f, y0 = (int)y0f;
    int4 idx; float4 w4;
    float msum = 0.0f;
    {
      int xi = x0, yi = y0;
      bool inb = (xi >= 0) & (xi < WS_DIM) & (yi >= 0) & (yi < HS_DIM);
      float wk = inb ? wx0 * wy0 : 0.0f;
      msum += wk;
      idx.x = min(max(yi, 0), HS_DIM - 1) * WS_DIM + min(max(xi, 0), WS_DIM - 1);
      w4.x = wk;
    }
    {
      int xi = x0, yi = y0 + 1;
      bool inb = (xi >= 0) & (xi < WS_DIM) & (yi >= 0) & (yi < HS_DIM);
      float wk = inb ? wx0 * wy1 : 0.0f;
      msum += wk;
      idx.y = min(max(yi, 0), HS_DIM - 1) * WS_DIM + min(max(xi, 0), WS_DIM - 1);
      w4.y = wk;
    }
    {
      int xi = x0 + 1, yi = y0;
      bool inb = (xi >= 0) & (xi < WS_DIM) & (yi >= 0) & (yi < HS_DIM);
      float wk = inb ? wx1 * wy0 : 0.0f;
      msum += wk;
      idx.z = min(max(yi, 0), HS_DIM - 1) * WS_DIM + min(max(xi, 0), WS_DIM - 1);
      w4.z = wk;
    }
    {
      int xi = x0 + 1, yi = y0 + 1;
      bool inb = (xi >= 0) & (xi < WS_DIM) & (yi >= 0) & (yi < HS_DIM);
      float wk = inb ? wx1 * wy1 : 0.0f;
      msum += wk;
      idx.w = min(max(yi, 0), HS_DIM - 1) * WS_DIM + min(max(xi, 0), WS_DIM - 1);
      w4.w = wk;
    }
    float cm  = (msum < 0.9999f) ? 0.0f : 1.0f;
    float cmm = cm * mval;
    s_idx[po][s] = idx;
    s_w[po][s]   = w4;
    s_cmm[po][s] = cmm;
    cmo[((size_t)n * S + s) * P + pp] = cmm;   // store directly
  }
  __syncthreads();

  // ---------------- phase 2 ----------------
  int cg = lane & 3;    // 4 lanes per sample; lane cg owns ch {j*32+cg*8..+8}
  int sl = lane >> 2;   // 16 samples per round
  float frv[4][8];
#pragma unroll
  for (int j = 0; j < 4; ++j) {
    float4 a = *reinterpret_cast<const float4*>(&fr_lds[wv][j * 32 + cg * 8]);
    float4 bq = *reinterpret_cast<const float4*>(&fr_lds[wv][j * 32 + cg * 8 + 4]);
    frv[j][0] = a.x; frv[j][1] = a.y; frv[j][2] = a.z; frv[j][3] = a.w;
    frv[j][4] = bq.x; frv[j][5] = bq.y; frv[j][6] = bq.z; frv[j][7] = bq.w;
  }
  const __half* fsb = fs_h + (size_t)n * Q * C + cg * 8;
  unsigned char* mystg = &stg[wv][0];

#pragma unroll 1
  for (int r = 0; r < 4; ++r) {
    int s = r * 16 + sl;
    int4   id4 = s_idx[wv][s];
    float4 w4  = s_w[wv][s];
    float  cms = s_cmm[wv][s];
    const __half* q0 = fsb + (size_t)id4.x * C;
    const __half* q1 = fsb + (size_t)id4.y * C;
    const __half* q2 = fsb + (size_t)id4.z * C;
    const __half* q3 = fsb + (size_t)id4.w * C;

    // keep prior iter's ds_reads strictly before this iter's LDS overwrite
    __builtin_amdgcn_sched_barrier(0);
    // issue all 16 gathers (no dest regs -> compiler cannot sink these)
#pragma unroll
    for (int j = 0; j < 4; ++j) gload_lds16(q0 + j * 32, mystg + (0 * 4 + j) * 1024);
#pragma unroll
    for (int j = 0; j < 4; ++j) gload_lds16(q1 + j * 32, mystg + (1 * 4 + j) * 1024);
#pragma unroll
    for (int j = 0; j < 4; ++j) gload_lds16(q2 + j * 32, mystg + (2 * 4 + j) * 1024);
#pragma unroll
    for (int j = 0; j < 4; ++j) gload_lds16(q3 + j * 32, mystg + (3 * 4 + j) * 1024);

    float d0 = 0.0f, d1 = 0.0f, d2 = 0.0f, d3 = 0.0f;
    asm volatile("s_waitcnt vmcnt(8)" ::: "memory");   // k0,k1 landed
#pragma unroll
    for (int j = 0; j < 4; ++j) {
      const __half2* h0 = reinterpret_cast<const __half2*>(mystg + (0 * 4 + j) * 1024 + lane * 16);
      const __half2* h1 = reinterpret_cast<const __half2*>(mystg + (1 * 4 + j) * 1024 + lane * 16);
#pragma unroll
      for (int i = 0; i < 4; ++i) {
        float2 f0 = __half22float2(h0[i]);
        float2 f1 = __half22float2(h1[i]);
        d0 = fmaf(frv[j][2 * i], f0.x, d0);
        d0 = fmaf(frv[j][2 * i + 1], f0.y, d0);
        d1 = fmaf(frv[j][2 * i], f1.x, d1);
        d1 = fmaf(frv[j][2 * i + 1], f1.y, d1);
      }
    }
    asm volatile("s_waitcnt vmcnt(0)" ::: "memory");   // k2,k3 landed
#pragma unroll
    for (int j = 0; j < 4; ++j) {
      const __half2* h2 = reinterpret_cast<const __half2*>(mystg + (2 * 4 + j) * 1024 + lane * 16);
      const __half2* h3 = reinterpret_cast<const __half2*>(mystg + (3 * 4 + j) * 1024 + lane * 16);
#pragma unroll
      for (int i = 0; i < 4; ++i) {
        float2 f2 = __half22float2(h2[i]);
        float2 f3 = __half22float2(h3[i]);
        d2 = fmaf(frv[j][2 * i], f2.x, d2);
        d2 = fmaf(frv[j][2 * i + 1], f2.y, d2);
        d3 = fmaf(frv[j][2 * i], f3.x, d3);
        d3 = fmaf(frv[j][2 * i + 1], f3.y, d3);
      }
    }
    float acc = fmaf(w4.x, d0, 0.0f);
    acc = fmaf(w4.y, d1, acc);
    acc = fmaf(w4.z, d2, acc);
    acc = fmaf(w4.w, d3, acc);
    // reduce across the 4 channel-group lanes
    acc += __shfl_xor(acc, 1);
    acc += __shfl_xor(acc, 2);
    if (cg == 0) s_out[wv][s] = acc * cms;
  }
  __syncthreads();
  {
    int s = t >> 2, w2 = t & 3;
    out[((size_t)n * S + s) * P + (p_base + w2)] = s_out[w2][s];
  }
}

extern "C" void kernel_launch(void* const* d_in, const int* in_sizes, int n_in,
                              void* d_out, int out_size, void* d_ws, size_t ws_size,
                              hipStream_t stream) {
  const float* feat_ref = (const float*)d_in[0];  // (4,128,64,64)
  const float* feat_src = (const float*)d_in[1];  // (4,128,64,64)
  const float* grids    = (const float*)d_in[2];  // (4,64,2,64,64)
  const float* mask     = (const float*)d_in[3];  // (4,64,64,64)
  __half* ws = (__half*)d_ws;                     // needs 4MB
  float* out = (float*)d_out;                     // out: 1,048,576 floats
  float* cmo = out + (size_t)NB * S * P;          // then corr_mask

  transpose_fs_h<<<1024, 256, 0, stream>>>(feat_src, ws);
  corr_main<<<4096, 256, 0, stream>>>(ws, feat_ref, grids, mask, out, cmo);
}